// Round 1
// baseline (1097.700 us; speedup 1.0000x reference)
//
#include <hip/hip_runtime.h>

#define NROWS 32768
#define DIM   128
#define KCODES 4096
#define DECAYF 0.8f
#define EPSF 1e-5f
#define COMMITW 0.25f

// ---------------- e2[k] = sum_d embed[k][d]^2 ----------------
__global__ __launch_bounds__(256) void e2_kernel(const float* __restrict__ embed,
                                                 float* __restrict__ e2) {
    int gid = blockIdx.x * blockDim.x + threadIdx.x;
    int wave = gid >> 6, lane = gid & 63;
    if (wave >= KCODES) return;
    float2 v = ((const float2*)(embed + (size_t)wave * DIM))[lane];
    float s = v.x * v.x + v.y * v.y;
    #pragma unroll
    for (int off = 32; off > 0; off >>= 1) s += __shfl_down(s, off, 64);
    if (lane == 0) e2[wave] = s;
}

// ---------------- argmax over codes of 2*x.e - |e|^2 ----------------
// Block: 128 threads (tx 0..7, ty 0..15). Tile: 64 rows x 32 codes/chunk.
// Thread micro-tile: 4 rows (r = ty + 16*i) x 4 codes (c = tx + 8*j).
// LDS stride 132 floats: within a wave (ty 0..7 or 8..15, tx 0..7) all 8 lanes
// sharing a ty read the SAME xs address (broadcast, free) and all 8 lanes
// sharing a tx read the SAME es address (broadcast, free).
#define BM 64
#define BC 32
#define LSTRIDE 132

__global__ __launch_bounds__(128) void argmax_kernel(const float* __restrict__ x,
                                                     const float* __restrict__ embed,
                                                     const float* __restrict__ e2,
                                                     int* __restrict__ ind) {
    __shared__ float xs[BM * LSTRIDE];     // 33792 B
    __shared__ float es[BC * LSTRIDE];     // 16896 B
    __shared__ float red_val[BM][8];       // 2048 B
    __shared__ int   red_idx[BM][8];       // 2048 B

    int tid = threadIdx.x;
    int tx = tid & 7;
    int ty = tid >> 3;
    int n0 = blockIdx.x * BM;

    // stage x tile: 64 rows x 32 float4
    for (int idx = tid; idx < BM * (DIM / 4); idx += 128) {
        int row = idx >> 5;
        int c4  = idx & 31;
        float4 v = ((const float4*)x)[(size_t)(n0 + row) * (DIM / 4) + c4];
        *(float4*)&xs[row * LSTRIDE + c4 * 4] = v;
    }

    float best[4];
    int   bidx[4];
    #pragma unroll
    for (int i = 0; i < 4; i++) { best[i] = -3.0e38f; bidx[i] = 0; }

    for (int kc = 0; kc < KCODES / BC; kc++) {
        int k0 = kc * BC;
        __syncthreads();   // protect es from previous chunk's readers
        for (int idx = tid; idx < BC * (DIM / 4); idx += 128) {
            int row = idx >> 5;
            int c4  = idx & 31;
            float4 v = ((const float4*)embed)[(size_t)(k0 + row) * (DIM / 4) + c4];
            *(float4*)&es[row * LSTRIDE + c4 * 4] = v;
        }
        __syncthreads();

        float acc[4][4];
        #pragma unroll
        for (int i = 0; i < 4; i++)
            #pragma unroll
            for (int j = 0; j < 4; j++) acc[i][j] = 0.f;

        #pragma unroll 4
        for (int d4 = 0; d4 < DIM / 4; d4++) {
            float4 xv[4], ev[4];
            #pragma unroll
            for (int i = 0; i < 4; i++)
                xv[i] = *(const float4*)&xs[(ty + 16 * i) * LSTRIDE + d4 * 4];
            #pragma unroll
            for (int j = 0; j < 4; j++)
                ev[j] = *(const float4*)&es[(tx + 8 * j) * LSTRIDE + d4 * 4];
            #pragma unroll
            for (int i = 0; i < 4; i++)
                #pragma unroll
                for (int j = 0; j < 4; j++) {
                    float a = acc[i][j];
                    a = fmaf(xv[i].x, ev[j].x, a);
                    a = fmaf(xv[i].y, ev[j].y, a);
                    a = fmaf(xv[i].z, ev[j].z, a);
                    a = fmaf(xv[i].w, ev[j].w, a);
                    acc[i][j] = a;
                }
        }

        // scores: 2*dot - e2[c]; codes ascend with j and kc -> strict > keeps
        // the lowest index on ties (matches argmax-first semantics)
        #pragma unroll
        for (int j = 0; j < 4; j++) {
            int c = k0 + tx + 8 * j;
            float ec = e2[c];
            #pragma unroll
            for (int i = 0; i < 4; i++) {
                float m = 2.0f * acc[i][j] - ec;
                if (m > best[i]) { best[i] = m; bidx[i] = c; }
            }
        }
    }

    __syncthreads();
    #pragma unroll
    for (int i = 0; i < 4; i++) {
        red_val[ty + 16 * i][tx] = best[i];
        red_idx[ty + 16 * i][tx] = bidx[i];
    }
    __syncthreads();
    if (tid < BM) {
        float bv = red_val[tid][0];
        int   bi = red_idx[tid][0];
        #pragma unroll
        for (int t = 1; t < 8; t++) {
            float v = red_val[tid][t];
            int   ii = red_idx[tid][t];
            if (v > bv || (v == bv && ii < bi)) { bv = v; bi = ii; }
        }
        ind[n0 + tid] = bi;
    }
}

// ---------------- gather quantize, scatter stats, commit loss ----------------
__global__ __launch_bounds__(256) void scatter_kernel(const float* __restrict__ x,
                                                      const float* __restrict__ embed,
                                                      const int* __restrict__ ind,
                                                      float* __restrict__ out_q,
                                                      float* __restrict__ out_ind,
                                                      float* __restrict__ bins,
                                                      float* __restrict__ esum,
                                                      float* __restrict__ loss) {
    int tid = threadIdx.x;
    int row = blockIdx.x * 2 + (tid >> 7);
    int d   = tid & 127;
    int k   = ind[row];
    float q  = embed[(size_t)k * DIM + d];
    float xv = x[(size_t)row * DIM + d];
    out_q[(size_t)row * DIM + d] = q;
    if (d == 0) {
        out_ind[row] = (float)k;
        atomicAdd(&bins[k], 1.0f);
    }
    atomicAdd(&esum[(size_t)k * DIM + d], xv);
    float diff = q - xv;
    float s = diff * diff;
    #pragma unroll
    for (int off = 32; off > 0; off >>= 1) s += __shfl_down(s, off, 64);
    __shared__ float ls[4];
    if ((tid & 63) == 0) ls[tid >> 6] = s;
    __syncthreads();
    if (tid == 0) atomicAdd(loss, ls[0] + ls[1] + ls[2] + ls[3]);
}

// ---------------- cs_new + n_total ----------------
__global__ __launch_bounds__(256) void cs_kernel(const float* __restrict__ cluster_size,
                                                 const float* __restrict__ bins,
                                                 float* __restrict__ out_cs,
                                                 float* __restrict__ ntot) {
    int k = blockIdx.x * 256 + threadIdx.x;
    float cs = cluster_size[k] * DECAYF + (1.0f - DECAYF) * bins[k];
    out_cs[k] = cs;
    float s = cs;
    #pragma unroll
    for (int off = 32; off > 0; off >>= 1) s += __shfl_down(s, off, 64);
    __shared__ float ls[4];
    if ((threadIdx.x & 63) == 0) ls[threadIdx.x >> 6] = s;
    __syncthreads();
    if (threadIdx.x == 0) atomicAdd(ntot, ls[0] + ls[1] + ls[2] + ls[3]);
}

// ---------------- embed_normalized + commit_loss finalize ----------------
__global__ __launch_bounds__(128) void norm_kernel(const float* __restrict__ embed_avg,
                                                   const float* __restrict__ esum,
                                                   const float* __restrict__ out_cs,
                                                   const float* __restrict__ ntot,
                                                   const float* __restrict__ loss,
                                                   float* __restrict__ out_norm,
                                                   float* __restrict__ out_loss) {
    int k = blockIdx.x;
    int d = threadIdx.x;
    float nt = *ntot;
    float cs = out_cs[k];
    float cluster = (cs + EPSF) / (nt + (float)KCODES * EPSF) * nt;
    size_t idx = (size_t)k * DIM + d;
    float ea = embed_avg[idx] * DECAYF + (1.0f - DECAYF) * esum[idx];
    out_norm[idx] = ea / cluster;
    if (k == 0 && d == 0) {
        *out_loss = COMMITW * (*loss) / (float)((size_t)NROWS * DIM);
    }
}

extern "C" void kernel_launch(void* const* d_in, const int* in_sizes, int n_in,
                              void* d_out, int out_size, void* d_ws, size_t ws_size,
                              hipStream_t stream) {
    const float* x            = (const float*)d_in[0];
    const float* embed        = (const float*)d_in[1];
    const float* cluster_size = (const float*)d_in[2];
    const float* embed_avg    = (const float*)d_in[3];

    float* out      = (float*)d_out;
    float* out_q    = out;                               // 32768*128 = 4194304
    float* out_ind  = out + 4194304;                     // 32768
    float* out_loss = out_ind + 32768;                   // 1
    float* out_cs   = out_loss + 1;                      // 4096
    float* out_norm = out_cs + 4096;                     // 524288

    char* ws = (char*)d_ws;
    int*   ind  = (int*)ws;                              // 131072 B
    float* e2   = (float*)(ws + 131072);                 // 16384 B
    float* bins = (float*)(ws + 147456);                 // 16384 B
    float* esum = (float*)(ws + 163840);                 // 2097152 B
    float* loss = (float*)(ws + 2260992);                // 4 B
    float* ntot = loss + 1;                              // 4 B

    // zero the accumulated regions: bins, esum, loss, ntot (contiguous)
    hipMemsetAsync(ws + 147456, 0, 16384 + 2097152 + 8, stream);

    e2_kernel<<<KCODES * 64 / 256, 256, 0, stream>>>(embed, e2);
    argmax_kernel<<<NROWS / BM, 128, 0, stream>>>(x, embed, e2, ind);
    scatter_kernel<<<NROWS / 2, 256, 0, stream>>>(x, embed, ind, out_q, out_ind,
                                                  bins, esum, loss);
    cs_kernel<<<KCODES / 256, 256, 0, stream>>>(cluster_size, bins, out_cs, ntot);
    norm_kernel<<<KCODES, 128, 0, stream>>>(embed_avg, esum, out_cs, ntot, loss,
                                            out_norm, out_loss);
}